// Round 9
// baseline (1193.918 us; speedup 1.0000x reference)
//
#include <hip/hip_runtime.h>
#include <hip/hip_bf16.h>

#define T_LEN 28
#define EMB   28
#define HID   256
#define NOUT  10
#define BATCH 32768
#define SCALE 2.8853900817779268f   // 2/ln2 folded into W2A/W1A/bias so tanh uses exp2 directly

typedef _Float16 f16x8 __attribute__((ext_vector_type(8)));
typedef _Float16 f16x4 __attribute__((ext_vector_type(4)));
typedef float    f32x4 __attribute__((ext_vector_type(4)));

// A-operand fragments for v_mfma_f32_16x16x32_f16 (row j = l&15, k = (l>>4)*8 + q):
// W2A: [jt(16)][kb(8)][l(64)][q(8)] -> A[j][k], j = jt*16+(l&15), k = kb*32+(l>>4)*8+q, scaled by SCALE
// W1A: [jt(16)][l(64)][q(8)]        -> A[j][e], e = (l>>4)*8+q
//      e==28 carries SCALE*(b1+b2) (matched by x-slot 1.0), e>28 zero.
__global__ __launch_bounds__(256) void prep_kernel(
    const float* __restrict__ W1, const float* __restrict__ W2,
    const float* __restrict__ b1, const float* __restrict__ b2,
    _Float16* __restrict__ W2A, _Float16* __restrict__ W1A) {
    int idx = blockIdx.x * 256 + threadIdx.x;
    if (idx < 65536) {
        int q  = idx & 7;
        int lm = (idx >> 3) & 63;
        int kb = (idx >> 9) & 7;
        int jt = idx >> 12;
        int j  = jt * 16 + (lm & 15);
        int k  = kb * 32 + (lm >> 4) * 8 + q;
        W2A[idx] = (_Float16)(SCALE * W2[j * HID + k]);
    }
    if (idx < 8192) {
        int q  = idx & 7;
        int lm = (idx >> 3) & 63;
        int jt = idx >> 9;
        int j  = jt * 16 + (lm & 15);
        int e  = (lm >> 4) * 8 + q;
        float v = (e < EMB) ? SCALE * W1[j * EMB + e]
                            : (e == EMB ? SCALE * (b1[j] + b2[j]) : 0.f);
        W1A[idx] = (_Float16)v;
    }
}

// Block = 16 batch rows, 256 thr = 4 waves (1 wave/SIMD). Wave owns 64 feature cols
// (4 j-tiles of 16) -> 4 independent MFMA acc chains. LDS only 16 KB (h dbuf) and
// ~210 unified regs -> 8 blocks/CU co-resident (launch_bounds(256,8)): 8 independent
// barrier domains per SIMD hide each other's tanh/barrier phases. Grid 2048 = 8/CU,
// exactly one round. x read from global per step with 1-step prefetch (8 regs).
// h LDS k-major chunks: chunk c (k=c*8..c*8+7) at c*256 + row*16;
// B-frag read (window kb) = base + l*16 + kb*1024 (linear 16B/lane, conflict-free).
__global__ __launch_bounds__(256, 8) void rnn_kernel(
    const float* __restrict__ seq,
    const _Float16* __restrict__ W2A,
    const _Float16* __restrict__ W1A,
    const float* __restrict__ W3,
    const float* __restrict__ b3,
    float* __restrict__ out)
{
    __shared__ __align__(16) char hls[2][8192];

    const int tid = threadIdx.x;
    const int l   = tid & 63;
    const int wv  = tid >> 6;          // 0..3
    const int lr  = l & 15;
    const int lg  = l >> 4;
    const int r0  = blockIdx.x * 16;

    // W2/W1 A-fragments: 4 j-tiles (jt = wv*4 + a) -> w2f 128 regs (AGPR half)
    f16x8 w2f[4][8];
#pragma unroll
    for (int a = 0; a < 4; ++a)
#pragma unroll
        for (int kb = 0; kb < 8; ++kb)
            w2f[a][kb] = *(const f16x8*)(W2A + ((((wv * 4 + a) * 8 + kb) * 64 + l) * 8));
    f16x8 w1f[4];
#pragma unroll
    for (int a = 0; a < 4; ++a)
        w1f[a] = *(const f16x8*)(W1A + (((wv * 4 + a) * 64 + l) * 8));

    // LDS write offsets: C-quad of tile a holds (i=lr, j = jt*16 + lg*4 + r)
    // -> chunk c = jt*2 + (lg>>1), byte c*256 + lr*16 + (lg&1)*8
    int wOff[4];
#pragma unroll
    for (int a = 0; a < 4; ++a)
        wOff[a] = (((wv * 4 + a) * 2 + (lg >> 1)) * 16 + lr) * 16 + (lg & 1) * 8;

    const float* rowp = seq + (size_t)(r0 + lr) * (T_LEN * EMB) + lg * 8;

    auto tanh4 = [&](const f32x4& a4) -> f16x4 {
        f16x4 hv;
#pragma unroll
        for (int r = 0; r < 4; ++r) {
            float e  = __builtin_amdgcn_exp2f(a4[r]);    // acc pre-scaled: = e^(2y)
            float rc = __builtin_amdgcn_rcpf(e + 1.f);
            hv[r] = (_Float16)__builtin_fmaf(-2.f, rc, 1.f);
        }
        return hv;
    };

    const f32x4 z = (f32x4){0.f, 0.f, 0.f, 0.f};

    // prefetch x(0): lane covers e = lg*8..+3 (rA) and lg*8+4..+7 (rB; lg==3 -> bias slot)
    f32x4 rA = *(const f32x4*)rowp;
    f32x4 rB = (f32x4){1.f, 0.f, 0.f, 0.f};
    if (lg < 3) rB = *(const f32x4*)(rowp + 4);

    for (int t = 0; t < T_LEN; ++t) {
        // convert this step's x to a B-frag
        f16x8 xf;
#pragma unroll
        for (int q = 0; q < 4; ++q) { xf[q] = (_Float16)rA[q]; xf[4 + q] = (_Float16)rB[q]; }

        // prefetch x(t+1) (consumed next iteration; hidden under this step's MFMAs)
        if (t < T_LEN - 1) {
            const float* sp = rowp + (t + 1) * EMB;
            rA = *(const f32x4*)sp;
            rB = (f32x4){1.f, 0.f, 0.f, 0.f};
            if (lg < 3) rB = *(const f32x4*)(sp + 4);
        }

        f32x4 acc[4];
        if (t > 0) {
            const char* rp = hls[(t + 1) & 1] + l * 16;
#pragma unroll
            for (int kb = 0; kb < 8; ++kb) {
                f16x8 hB = *(const f16x8*)(rp + kb * 1024);
#pragma unroll
                for (int a = 0; a < 4; ++a)
                    acc[a] = __builtin_amdgcn_mfma_f32_16x16x32_f16(
                                 w2f[a][kb], hB, (kb == 0) ? z : acc[a], 0, 0, 0);
            }
#pragma unroll
            for (int a = 0; a < 4; ++a)
                acc[a] = __builtin_amdgcn_mfma_f32_16x16x32_f16(w1f[a], xf, acc[a], 0, 0, 0);
        } else {
#pragma unroll
            for (int a = 0; a < 4; ++a)
                acc[a] = __builtin_amdgcn_mfma_f32_16x16x32_f16(w1f[a], xf, z, 0, 0, 0);
        }

        // tanh -> fp16 -> k-major LDS write (8B per tile)
        char* wb = hls[t & 1];
#pragma unroll
        for (int a = 0; a < 4; ++a)
            *(f16x4*)(wb + wOff[a]) = tanh4(acc[a]);
        __syncthreads();
    }

    // ---- head: out = h @ W3^T + b3 (final h in hls[(T_LEN-1)&1] = hls[1]) ----
    const char* hb = hls[(T_LEN - 1) & 1];
    for (int idx = tid; idx < 16 * NOUT; idx += 256) {
        int i = idx / NOUT;
        int o = idx - i * NOUT;
        float s = b3[o];
#pragma unroll
        for (int c = 0; c < 32; ++c) {
            f16x8 hv  = *(const f16x8*)(hb + c * 256 + i * 16);
            f32x4 w0  = *(const f32x4*)(W3 + o * HID + c * 8);
            f32x4 w1v = *(const f32x4*)(W3 + o * HID + c * 8 + 4);
#pragma unroll
            for (int q = 0; q < 4; ++q)
                s += (float)hv[q] * w0[q] + (float)hv[4 + q] * w1v[q];
        }
        out[(size_t)(r0 + i) * NOUT + o] = s;
    }
}

extern "C" void kernel_launch(void* const* d_in, const int* in_sizes, int n_in,
                              void* d_out, int out_size, void* d_ws, size_t ws_size,
                              hipStream_t stream) {
    const float* seq = (const float*)d_in[0];
    const float* W1  = (const float*)d_in[1];
    const float* b1  = (const float*)d_in[2];
    const float* W2  = (const float*)d_in[3];
    const float* b2  = (const float*)d_in[4];
    const float* W3  = (const float*)d_in[5];
    const float* b3  = (const float*)d_in[6];
    float* outp = (float*)d_out;

    _Float16* W2A = (_Float16*)d_ws;
    _Float16* W1A = (_Float16*)((char*)d_ws + 65536 * sizeof(_Float16));

    prep_kernel<<<256, 256, 0, stream>>>(W1, W2, b1, b2, W2A, W1A);
    rnn_kernel<<<BATCH / 16, 256, 0, stream>>>(seq, W2A, W1A, W3, b3, outp);
}

// Round 10
// 597.557 us; speedup vs baseline: 1.9980x; 1.9980x over previous
//
#include <hip/hip_runtime.h>
#include <hip/hip_bf16.h>

#define T_LEN 28
#define EMB   28
#define HID   256
#define NOUT  10
#define BATCH 32768
#define SCALE 2.8853900817779268f   // 2/ln2 folded into W2A/W1A/bias so tanh uses exp2 directly

typedef _Float16 f16x8 __attribute__((ext_vector_type(8)));
typedef _Float16 f16x4 __attribute__((ext_vector_type(4)));
typedef float    f32x4 __attribute__((ext_vector_type(4)));

// A-operand fragments for v_mfma_f32_16x16x32_f16 (row j = l&15, k = (l>>4)*8 + q):
// W2A: [jt(16)][kb(8)][l(64)][q(8)] -> A[j][k], j = jt*16+(l&15), k = kb*32+(l>>4)*8+q, scaled by SCALE
// W1A: [jt(16)][l(64)][q(8)]        -> A[j][e], e = (l>>4)*8+q
//      e==28 carries SCALE*(b1+b2) (matched by x-slot 1.0), e>28 zero.
__global__ __launch_bounds__(256) void prep_kernel(
    const float* __restrict__ W1, const float* __restrict__ W2,
    const float* __restrict__ b1, const float* __restrict__ b2,
    _Float16* __restrict__ W2A, _Float16* __restrict__ W1A) {
    int idx = blockIdx.x * 256 + threadIdx.x;
    if (idx < 65536) {
        int q  = idx & 7;
        int lm = (idx >> 3) & 63;
        int kb = (idx >> 9) & 7;
        int jt = idx >> 12;
        int j  = jt * 16 + (lm & 15);
        int k  = kb * 32 + (lm >> 4) * 8 + q;
        W2A[idx] = (_Float16)(SCALE * W2[j * HID + k]);
    }
    if (idx < 8192) {
        int q  = idx & 7;
        int lm = (idx >> 3) & 63;
        int jt = idx >> 9;
        int j  = jt * 16 + (lm & 15);
        int e  = (lm >> 4) * 8 + q;
        float v = (e < EMB) ? SCALE * W1[j * EMB + e]
                            : (e == EMB ? SCALE * (b1[j] + b2[j]) : 0.f);
        W1A[idx] = (_Float16)v;
    }
}

// Block = 16 batch rows, 256 thr = 4 waves (1 wave/SIMD). Wave owns 64 feature cols
// (4 j-tiles of 16) -> 4 independent MFMA acc chains. LDS 16 KB (h dbuf).
// launch_bounds(256,4): 4 waves/SIMD -> 512 unified regs/wave (2x our ~250 live set,
// no spill — r9's (256,8) gave 256/wave and demoted w2f to global reloads, FETCH 3.4GB).
// 4 co-resident blocks/CU = 4 independent barrier domains per SIMD: when one wave is
// in tanh/barrier, others feed the matrix pipe. Grid 2048 = exactly 2 rounds.
// h LDS k-major chunks: chunk c (k=c*8..c*8+7) at c*256 + row*16;
// B-frag read (window kb) = base + l*16 + kb*1024 (linear 16B/lane, conflict-free).
__global__ __launch_bounds__(256, 4) void rnn_kernel(
    const float* __restrict__ seq,
    const _Float16* __restrict__ W2A,
    const _Float16* __restrict__ W1A,
    const float* __restrict__ W3,
    const float* __restrict__ b3,
    float* __restrict__ out)
{
    __shared__ __align__(16) char hls[2][8192];

    const int tid = threadIdx.x;
    const int l   = tid & 63;
    const int wv  = tid >> 6;          // 0..3
    const int lr  = l & 15;
    const int lg  = l >> 4;
    const int r0  = blockIdx.x * 16;

    // W2/W1 A-fragments: 4 j-tiles (jt = wv*4 + a) -> w2f 128 regs (AGPR half)
    f16x8 w2f[4][8];
#pragma unroll
    for (int a = 0; a < 4; ++a)
#pragma unroll
        for (int kb = 0; kb < 8; ++kb)
            w2f[a][kb] = *(const f16x8*)(W2A + ((((wv * 4 + a) * 8 + kb) * 64 + l) * 8));
    f16x8 w1f[4];
#pragma unroll
    for (int a = 0; a < 4; ++a)
        w1f[a] = *(const f16x8*)(W1A + (((wv * 4 + a) * 64 + l) * 8));

    // LDS write offsets: C-quad of tile a holds (i=lr, j = jt*16 + lg*4 + r)
    // -> chunk c = jt*2 + (lg>>1), byte c*256 + lr*16 + (lg&1)*8
    int wOff[4];
#pragma unroll
    for (int a = 0; a < 4; ++a)
        wOff[a] = (((wv * 4 + a) * 2 + (lg >> 1)) * 16 + lr) * 16 + (lg & 1) * 8;

    const float* rowp = seq + (size_t)(r0 + lr) * (T_LEN * EMB) + lg * 8;

    auto tanh4 = [&](const f32x4& a4) -> f16x4 {
        f16x4 hv;
#pragma unroll
        for (int r = 0; r < 4; ++r) {
            float e  = __builtin_amdgcn_exp2f(a4[r]);    // acc pre-scaled: = e^(2y)
            float rc = __builtin_amdgcn_rcpf(e + 1.f);
            hv[r] = (_Float16)__builtin_fmaf(-2.f, rc, 1.f);
        }
        return hv;
    };

    const f32x4 z = (f32x4){0.f, 0.f, 0.f, 0.f};

    // prefetch x(0): lane covers e = lg*8..+3 (rA) and lg*8+4..+7 (rB; lg==3 -> bias slot)
    f32x4 rA = *(const f32x4*)rowp;
    f32x4 rB = (f32x4){1.f, 0.f, 0.f, 0.f};
    if (lg < 3) rB = *(const f32x4*)(rowp + 4);

    for (int t = 0; t < T_LEN; ++t) {
        // convert this step's x to a B-frag
        f16x8 xf;
#pragma unroll
        for (int q = 0; q < 4; ++q) { xf[q] = (_Float16)rA[q]; xf[4 + q] = (_Float16)rB[q]; }

        // prefetch x(t+1) (consumed next iteration; hidden under this step's MFMAs)
        if (t < T_LEN - 1) {
            const float* sp = rowp + (t + 1) * EMB;
            rA = *(const f32x4*)sp;
            rB = (f32x4){1.f, 0.f, 0.f, 0.f};
            if (lg < 3) rB = *(const f32x4*)(sp + 4);
        }

        f32x4 acc[4];
        if (t > 0) {
            const char* rp = hls[(t + 1) & 1] + l * 16;
#pragma unroll
            for (int kb = 0; kb < 8; ++kb) {
                f16x8 hB = *(const f16x8*)(rp + kb * 1024);
#pragma unroll
                for (int a = 0; a < 4; ++a)
                    acc[a] = __builtin_amdgcn_mfma_f32_16x16x32_f16(
                                 w2f[a][kb], hB, (kb == 0) ? z : acc[a], 0, 0, 0);
            }
#pragma unroll
            for (int a = 0; a < 4; ++a)
                acc[a] = __builtin_amdgcn_mfma_f32_16x16x32_f16(w1f[a], xf, acc[a], 0, 0, 0);
        } else {
#pragma unroll
            for (int a = 0; a < 4; ++a)
                acc[a] = __builtin_amdgcn_mfma_f32_16x16x32_f16(w1f[a], xf, z, 0, 0, 0);
        }

        // tanh -> fp16 -> k-major LDS write (8B per tile)
        char* wb = hls[t & 1];
#pragma unroll
        for (int a = 0; a < 4; ++a)
            *(f16x4*)(wb + wOff[a]) = tanh4(acc[a]);
        __syncthreads();
    }

    // ---- head: out = h @ W3^T + b3 (final h in hls[(T_LEN-1)&1] = hls[1]) ----
    const char* hb = hls[(T_LEN - 1) & 1];
    for (int idx = tid; idx < 16 * NOUT; idx += 256) {
        int i = idx / NOUT;
        int o = idx - i * NOUT;
        float s = b3[o];
#pragma unroll
        for (int c = 0; c < 32; ++c) {
            f16x8 hv  = *(const f16x8*)(hb + c * 256 + i * 16);
            f32x4 w0  = *(const f32x4*)(W3 + o * HID + c * 8);
            f32x4 w1v = *(const f32x4*)(W3 + o * HID + c * 8 + 4);
#pragma unroll
            for (int q = 0; q < 4; ++q)
                s += (float)hv[q] * w0[q] + (float)hv[4 + q] * w1v[q];
        }
        out[(size_t)(r0 + i) * NOUT + o] = s;
    }
}

extern "C" void kernel_launch(void* const* d_in, const int* in_sizes, int n_in,
                              void* d_out, int out_size, void* d_ws, size_t ws_size,
                              hipStream_t stream) {
    const float* seq = (const float*)d_in[0];
    const float* W1  = (const float*)d_in[1];
    const float* b1  = (const float*)d_in[2];
    const float* W2  = (const float*)d_in[3];
    const float* b2  = (const float*)d_in[4];
    const float* W3  = (const float*)d_in[5];
    const float* b3  = (const float*)d_in[6];
    float* outp = (float*)d_out;

    _Float16* W2A = (_Float16*)d_ws;
    _Float16* W1A = (_Float16*)((char*)d_ws + 65536 * sizeof(_Float16));

    prep_kernel<<<256, 256, 0, stream>>>(W1, W2, b1, b2, W2A, W1A);
    rnn_kernel<<<BATCH / 16, 256, 0, stream>>>(seq, W2A, W1A, W3, b3, outp);
}

// Round 11
// 206.900 us; speedup vs baseline: 5.7705x; 2.8881x over previous
//
#include <hip/hip_runtime.h>
#include <hip/hip_bf16.h>

#define T_LEN 28
#define EMB   28
#define HID   256
#define NOUT  10
#define BATCH 32768
#define SCALE 2.8853900817779268f   // 2/ln2 folded into W2A/W1A/bias so tanh uses exp2 directly

typedef _Float16 f16x8  __attribute__((ext_vector_type(8)));
typedef _Float16 f16x4  __attribute__((ext_vector_type(4)));
typedef float    f32x4  __attribute__((ext_vector_type(4)));
typedef float    f32x16 __attribute__((ext_vector_type(16)));

// A-operand fragments for v_mfma_f32_32x32x16_f16 (row j = l&31, k = (l>>5)*8 + q):
// W2A: [jt(8)][kb(16)][l(64)][q(8)] -> A[j][k], j = jt*32+(l&31), k = kb*16+(l>>5)*8+q, scaled by SCALE
// W1A: [jt(8)][kb(2)][l(64)][q(8)]  -> A[j][e], e = kb*16+(l>>5)*8+q
//      e==28 carries SCALE*(b1+b2) (matched by x-slot 1.0), e>28 zero.
__global__ __launch_bounds__(256) void prep_kernel(
    const float* __restrict__ W1, const float* __restrict__ W2,
    const float* __restrict__ b1, const float* __restrict__ b2,
    _Float16* __restrict__ W2A, _Float16* __restrict__ W1A) {
    int idx = blockIdx.x * 256 + threadIdx.x;
    if (idx < 65536) {
        int q  = idx & 7;
        int lm = (idx >> 3) & 63;
        int kb = (idx >> 9) & 15;
        int jt = idx >> 13;
        int j  = jt * 32 + (lm & 31);
        int k  = kb * 16 + (lm >> 5) * 8 + q;
        W2A[idx] = (_Float16)(SCALE * W2[j * HID + k]);
    }
    if (idx < 8192) {
        int q  = idx & 7;
        int lm = (idx >> 3) & 63;
        int kb = (idx >> 9) & 1;
        int jt = idx >> 10;
        int j  = jt * 32 + (lm & 31);
        int e  = kb * 16 + (lm >> 5) * 8 + q;
        float v = (e < EMB) ? SCALE * W1[j * EMB + e]
                            : (e == EMB ? SCALE * (b1[j] + b2[j]) : 0.f);
        W1A[idx] = (_Float16)v;
    }
}

// Block = 64 batch rows, 512 thr = 8 waves. Wave wv owns j-tile wv (32 feature cols)
// over BOTH 32-row i-tiles. W2 MFMA fragments live in LDS (128 KB) -- NOT registers:
// per-wave live set ~130 regs, no remat/spill (the r4-r10 failure mode). One block/CU
// (LDS 160 KB), long ~1163-cy MFMA phases amortize the per-step barriers.
// LDS: W2L [0,128K): fragment order [jt][kb][l][q] (straight copy of W2A);
//      hL  [128K,160K): k-major chunks, chunk c (feat c*8..+7) at (c*64+i)*16.
// All ds_reads lane-linear conflict-free. x loaded from global at step top (covered
// by k-loop). Staging of W2L overlaps the t=0 (x-only) step.
__global__ __launch_bounds__(512, 2) void rnn_kernel(
    const float* __restrict__ seq,
    const _Float16* __restrict__ W2A,
    const _Float16* __restrict__ W1A,
    const float* __restrict__ W3,
    const float* __restrict__ b3,
    float* __restrict__ out)
{
    __shared__ __align__(16) char lds_[163840];
    char* const w2l = lds_;
    char* const hl  = lds_ + 131072;

    const int tid = threadIdx.x;
    const int l   = tid & 63;
    const int wv  = tid >> 6;          // 0..7 = j-tile
    const int lo  = l & 31;
    const int hi  = l >> 5;
    const int r0  = blockIdx.x * 64;

    // ---- stage W2 fragments -> LDS (straight 128 KB copy, coalesced) ----
    {
        const int4* src = (const int4*)W2A;
        int4*       dst = (int4*)w2l;
#pragma unroll
        for (int i = 0; i < 16; ++i)
            dst[tid + i * 512] = src[tid + i * 512];
    }

    // W1 fragments in registers (8 regs)
    f16x8 w1f[2];
#pragma unroll
    for (int kb = 0; kb < 2; ++kb)
        w1f[kb] = *(const f16x8*)(W1A + (((wv * 2 + kb) * 64 + l) * 8));

    const float* rowp0 = seq + (size_t)(r0 + lo) * (T_LEN * EMB);        // i-tile 0
    const float* rowp1 = seq + (size_t)(r0 + 32 + lo) * (T_LEN * EMB);   // i-tile 1

    // k-loop base addresses
    const char* wbase = w2l + wv * 16384 + l * 16;            // + kb*1024
    const char* hbase = hl + hi * 1024 + lo * 16;             // + kb*2048 + b*512
    // h write offsets: quad q of i-tile b -> ((wv*4+q)*64 + b*32 + lo)*16 + hi*8
    const int wOffBase = ((wv * 4) * 64 + lo) * 16 + hi * 8;

    auto tanh4 = [&](float v0, float v1, float v2, float v3) -> f16x4 {
        f16x4 hv;
        float vv[4] = {v0, v1, v2, v3};
#pragma unroll
        for (int r = 0; r < 4; ++r) {
            float e  = __builtin_amdgcn_exp2f(vv[r]);       // acc pre-scaled: = e^(2y)
            float rc = __builtin_amdgcn_rcpf(e + 1.f);
            vv[r] = __builtin_fmaf(-2.f, rc, 1.f);
        }
#pragma unroll
        for (int r = 0; r < 4; ++r) hv[r] = (_Float16)vv[r];
        return hv;
    };

    const f32x16 z = (f32x16)(0.f);

    __syncthreads();   // W2L staged (t=0 below doesn't read it; barrier also orders h writes)

    for (int t = 0; t < T_LEN; ++t) {
        // ---- issue this step's x loads (consumed after the k-loop: ~1100 cy cover) ----
        const float* s0 = rowp0 + t * EMB;
        const float* s1 = rowp1 + t * EMB;
        f32x4 a0 = *(const f32x4*)(s0 + hi * 8);
        f32x4 a1 = *(const f32x4*)(s0 + hi * 8 + 4);
        f32x4 a2 = *(const f32x4*)(s0 + 16 + hi * 8);
        f32x4 a3 = (f32x4){1.f, 0.f, 0.f, 0.f};              // e=28 bias, 29-31 zero
        if (hi == 0) a3 = *(const f32x4*)(s0 + 20);
        f32x4 b0 = *(const f32x4*)(s1 + hi * 8);
        f32x4 b1v = *(const f32x4*)(s1 + hi * 8 + 4);
        f32x4 b2v = *(const f32x4*)(s1 + 16 + hi * 8);
        f32x4 b3v = (f32x4){1.f, 0.f, 0.f, 0.f};
        if (hi == 0) b3v = *(const f32x4*)(s1 + 20);

        f32x16 acc0, acc1;
        if (t > 0) {
            // ---- h recurrence: 16 k-windows, A from LDS, B(h) from LDS ----
#pragma unroll
            for (int kb = 0; kb < 16; ++kb) {
                f16x8 wa = *(const f16x8*)(wbase + kb * 1024);
                f16x8 h0 = *(const f16x8*)(hbase + kb * 2048);
                f16x8 h1 = *(const f16x8*)(hbase + kb * 2048 + 512);
                acc0 = __builtin_amdgcn_mfma_f32_32x32x16_f16(wa, h0, (kb == 0) ? z : acc0, 0, 0, 0);
                acc1 = __builtin_amdgcn_mfma_f32_32x32x16_f16(wa, h1, (kb == 0) ? z : acc1, 0, 0, 0);
            }
        }

        // ---- x projection ----
        f16x8 x00, x01, x10, x11;
#pragma unroll
        for (int q = 0; q < 4; ++q) {
            x00[q] = (_Float16)a0[q]; x00[4 + q] = (_Float16)a1[q];
            x01[q] = (_Float16)a2[q]; x01[4 + q] = (_Float16)a3[q];
            x10[q] = (_Float16)b0[q]; x10[4 + q] = (_Float16)b1v[q];
            x11[q] = (_Float16)b2v[q]; x11[4 + q] = (_Float16)b3v[q];
        }
        acc0 = __builtin_amdgcn_mfma_f32_32x32x16_f16(w1f[0], x00, (t == 0) ? z : acc0, 0, 0, 0);
        acc0 = __builtin_amdgcn_mfma_f32_32x32x16_f16(w1f[1], x01, acc0, 0, 0, 0);
        acc1 = __builtin_amdgcn_mfma_f32_32x32x16_f16(w1f[0], x10, (t == 0) ? z : acc1, 0, 0, 0);
        acc1 = __builtin_amdgcn_mfma_f32_32x32x16_f16(w1f[1], x11, acc1, 0, 0, 0);

        // ---- tanh -> fp16 quads ----
        f16x4 hq0[4], hq1[4];
#pragma unroll
        for (int q = 0; q < 4; ++q) {
            hq0[q] = tanh4(acc0[q * 4], acc0[q * 4 + 1], acc0[q * 4 + 2], acc0[q * 4 + 3]);
            hq1[q] = tanh4(acc1[q * 4], acc1[q * 4 + 1], acc1[q * 4 + 2], acc1[q * 4 + 3]);
        }

        __syncthreads();   // all reads of h(t-1) done (and staging/t-1 writes ordered)

#pragma unroll
        for (int q = 0; q < 4; ++q) {
            *(f16x4*)(hl + wOffBase + q * 1024)       = hq0[q];   // i-tile 0
            *(f16x4*)(hl + wOffBase + q * 1024 + 512) = hq1[q];   // i-tile 1
        }
        __syncthreads();   // h(t) visible
    }

    // ---- head: out = h @ W3^T + b3 over 64 rows (final h in hl) ----
    for (int idx = tid; idx < 64 * NOUT; idx += 512) {
        int i = idx / NOUT;
        int o = idx - i * NOUT;
        float s = b3[o];
#pragma unroll
        for (int c = 0; c < 32; ++c) {
            f16x8 hv  = *(const f16x8*)(hl + (c * 64 + i) * 16);
            f32x4 w0  = *(const f32x4*)(W3 + o * HID + c * 8);
            f32x4 w1v = *(const f32x4*)(W3 + o * HID + c * 8 + 4);
#pragma unroll
            for (int q = 0; q < 4; ++q)
                s += (float)hv[q] * w0[q] + (float)hv[4 + q] * w1v[q];
        }
        out[(size_t)(r0 + i) * NOUT + o] = s;
    }
}

extern "C" void kernel_launch(void* const* d_in, const int* in_sizes, int n_in,
                              void* d_out, int out_size, void* d_ws, size_t ws_size,
                              hipStream_t stream) {
    const float* seq = (const float*)d_in[0];
    const float* W1  = (const float*)d_in[1];
    const float* b1  = (const float*)d_in[2];
    const float* W2  = (const float*)d_in[3];
    const float* b2  = (const float*)d_in[4];
    const float* W3  = (const float*)d_in[5];
    const float* b3  = (const float*)d_in[6];
    float* outp = (float*)d_out;

    _Float16* W2A = (_Float16*)d_ws;
    _Float16* W1A = (_Float16*)((char*)d_ws + 65536 * sizeof(_Float16));

    prep_kernel<<<256, 256, 0, stream>>>(W1, W2, b1, b2, W2A, W1A);
    rnn_kernel<<<BATCH / 64, 512, 0, stream>>>(seq, W2A, W1A, W3, b3, outp);
}